// Round 1
// baseline (141.505 us; speedup 1.0000x reference)
//
#include <hip/hip_runtime.h>

// Problem constants (from reference): B=8, H=1024, NIN=256, C=128, E=16
#define B_    8
#define H_    1024
#define NIN_  256
#define C_    128
#define E_    16

// ---------------------------------------------------------------------------
// Kernel 1: compute s_t[b,h] = sum_n vt[n] * x[b,n,h]  (and s_p with vp)
//   vt[n] = sum_c Wcat[E+c]   * Wt[c*NIN+n]
//   vp[n] = sum_c Wcat[E+C+c] * Wp[c*NIN+n]
// Grid: B * (H/64) = 128 blocks, 256 threads.
//   Phase A: thread n computes vt[n], vp[n] into LDS (coalesced column reads).
//   Phase B: threads (hl = tid&63, ng = tid>>6) each accumulate 64 n's for one
//            h, coalesced across hl; LDS tree-reduce over the 4 n-groups.
// ---------------------------------------------------------------------------
__global__ __launch_bounds__(256) void compute_s_kernel(
    const float* __restrict__ x,     // (B, NIN, H)
    const float* __restrict__ Wt,    // (C, NIN)
    const float* __restrict__ Wp,    // (C, NIN)
    const float* __restrict__ Wcat,  // (E + 2C,)
    float* __restrict__ s_t,         // (B, H)
    float* __restrict__ s_p)         // (B, H)
{
    __shared__ float vt[NIN_];
    __shared__ float vp[NIN_];
    __shared__ float red_t[4][64];
    __shared__ float red_p[4][64];

    const int tid = threadIdx.x;

    // Phase A: fold Wcat into Wt/Wp columns. tid == n (NIN == blockDim).
    {
        float at = 0.f, ap = 0.f;
        #pragma unroll 4
        for (int c = 0; c < C_; ++c) {
            at += Wcat[E_ + c]      * Wt[c * NIN_ + tid];
            ap += Wcat[E_ + C_ + c] * Wp[c * NIN_ + tid];
        }
        vt[tid] = at;
        vp[tid] = ap;
    }
    __syncthreads();

    // Phase B
    const int b  = blockIdx.x >> 4;            // H/64 = 16 chunks per b
    const int h0 = (blockIdx.x & 15) << 6;     // *64
    const int hl = tid & 63;
    const int ng = tid >> 6;                   // 0..3
    const int h  = h0 + hl;

    const float* xb = x + (size_t)b * NIN_ * H_ + h;
    float at = 0.f, ap = 0.f;
    const int n0 = ng << 6;
    #pragma unroll 8
    for (int k = 0; k < 64; ++k) {
        const int n = n0 + k;
        const float xv = xb[(size_t)n * H_];
        at += vt[n] * xv;
        ap += vp[n] * xv;
    }
    red_t[ng][hl] = at;
    red_p[ng][hl] = ap;
    __syncthreads();

    if (ng == 0) {
        const float st = red_t[0][hl] + red_t[1][hl] + red_t[2][hl] + red_t[3][hl];
        const float sp = red_p[0][hl] + red_p[1][hl] + red_p[2][hl] + red_p[3][hl];
        s_t[b * H_ + h] = st;
        s_p[b * H_ + h] = sp;
    }
}

// ---------------------------------------------------------------------------
// Kernel 2: out[b,h,w] = sum_e Wcat[e]*edges[b,e,h,w] + s_t[b,h] + s_p[b,w]
// float4-vectorized over w. Grid-stride over B*H*H/4 = 2^21 float4 elements.
// ---------------------------------------------------------------------------
__global__ __launch_bounds__(256) void affinity_main_kernel(
    const float* __restrict__ edges,  // (B, E, H, H)
    const float* __restrict__ Wcat,   // first E entries = w_e
    const float* __restrict__ s_t,    // (B, H)
    const float* __restrict__ s_p,    // (B, H)
    float* __restrict__ out)          // (B, H, H) flat
{
    float we[E_];
    #pragma unroll
    for (int e = 0; e < E_; ++e) we[e] = Wcat[e];

    const int HH4    = (H_ * H_) / 4;   // 262144 = 2^18 float4 per (b,e) plane
    const int total4 = B_ * HH4;        // 2^21
    const int stride = gridDim.x * blockDim.x;

    const float4* edges4 = (const float4*)edges;
    const float4* s_p4   = (const float4*)s_p;
    float4*       out4   = (float4*)out;

    for (int v = blockIdx.x * blockDim.x + threadIdx.x; v < total4; v += stride) {
        const int b   = v >> 18;           // / HH4
        const int rem = v & (HH4 - 1);
        const int h   = rem >> 8;          // / (H/4)
        const int w4  = rem & 255;

        const float4* ebase = edges4 + (size_t)b * E_ * HH4 + rem;

        float4 acc = make_float4(0.f, 0.f, 0.f, 0.f);
        #pragma unroll
        for (int e = 0; e < E_; ++e) {
            const float4 ev = ebase[(size_t)e * HH4];
            acc.x += we[e] * ev.x;
            acc.y += we[e] * ev.y;
            acc.z += we[e] * ev.z;
            acc.w += we[e] * ev.w;
        }

        const float  st = s_t[b * H_ + h];
        const float4 sp = s_p4[b * (H_ / 4) + w4];
        acc.x += st + sp.x;
        acc.y += st + sp.y;
        acc.z += st + sp.z;
        acc.w += st + sp.w;

        out4[v] = acc;
    }
}

extern "C" void kernel_launch(void* const* d_in, const int* in_sizes, int n_in,
                              void* d_out, int out_size, void* d_ws, size_t ws_size,
                              hipStream_t stream) {
    // Inputs in setup_inputs() order:
    //   0: adj  (B,H,H)    f32 -- UNUSED by the reference
    //   1: edges(B,E,H,H)  f32
    //   2: x    (B,NIN,H)  f32
    //   3: Wt   (C,NIN)    f32
    //   4: Wp   (C,NIN)    f32
    //   5: Wcat (E+2C,)    f32
    const float* edges = (const float*)d_in[1];
    const float* x     = (const float*)d_in[2];
    const float* Wt    = (const float*)d_in[3];
    const float* Wp    = (const float*)d_in[4];
    const float* Wcat  = (const float*)d_in[5];
    float* out = (float*)d_out;

    float* s_t = (float*)d_ws;            // B*H floats = 32 KB
    float* s_p = s_t + B_ * H_;           // B*H floats = 32 KB

    compute_s_kernel<<<B_ * (H_ / 64), 256, 0, stream>>>(x, Wt, Wp, Wcat, s_t, s_p);

    affinity_main_kernel<<<2048, 256, 0, stream>>>(edges, Wcat, s_t, s_p, out);
}

// Round 3
// 101.701 us; speedup vs baseline: 1.3914x; 1.3914x over previous
//
#include <hip/hip_runtime.h>

// Problem constants (from reference): B=8, H=1024, NIN=256, C=128, E=16
#define B_    8
#define H_    1024
#define NIN_  256
#define C_    128
#define E_    16

// clang native 4-float vector — required by __builtin_nontemporal_load/store
typedef float f4_t __attribute__((ext_vector_type(4)));

// ---------------------------------------------------------------------------
// Kernel 1: compute s_t[b,h] = sum_n vt[n] * x[b,n,h]  (and s_p with vp)
//   vt[n] = sum_c Wcat[E+c]   * Wt[c*NIN+n]
//   vp[n] = sum_c Wcat[E+C+c] * Wp[c*NIN+n]
// ---------------------------------------------------------------------------
__global__ __launch_bounds__(256) void compute_s_kernel(
    const float* __restrict__ x,     // (B, NIN, H)
    const float* __restrict__ Wt,    // (C, NIN)
    const float* __restrict__ Wp,    // (C, NIN)
    const float* __restrict__ Wcat,  // (E + 2C,)
    float* __restrict__ s_t,         // (B, H)
    float* __restrict__ s_p)         // (B, H)
{
    __shared__ float vt[NIN_];
    __shared__ float vp[NIN_];
    __shared__ float red_t[4][64];
    __shared__ float red_p[4][64];

    const int tid = threadIdx.x;

    // Phase A: fold Wcat into Wt/Wp columns. tid == n (NIN == blockDim).
    {
        float at = 0.f, ap = 0.f;
        #pragma unroll 4
        for (int c = 0; c < C_; ++c) {
            at += Wcat[E_ + c]      * Wt[c * NIN_ + tid];
            ap += Wcat[E_ + C_ + c] * Wp[c * NIN_ + tid];
        }
        vt[tid] = at;
        vp[tid] = ap;
    }
    __syncthreads();

    // Phase B
    const int b  = blockIdx.x >> 4;            // H/64 = 16 chunks per b
    const int h0 = (blockIdx.x & 15) << 6;     // *64
    const int hl = tid & 63;
    const int ng = tid >> 6;                   // 0..3
    const int h  = h0 + hl;

    const float* xb = x + (size_t)b * NIN_ * H_ + h;
    float at = 0.f, ap = 0.f;
    const int n0 = ng << 6;
    #pragma unroll 8
    for (int k = 0; k < 64; ++k) {
        const int n = n0 + k;
        const float xv = xb[(size_t)n * H_];
        at += vt[n] * xv;
        ap += vp[n] * xv;
    }
    red_t[ng][hl] = at;
    red_p[ng][hl] = ap;
    __syncthreads();

    if (ng == 0) {
        const float st = red_t[0][hl] + red_t[1][hl] + red_t[2][hl] + red_t[3][hl];
        const float sp = red_p[0][hl] + red_p[1][hl] + red_p[2][hl] + red_p[3][hl];
        s_t[b * H_ + h] = st;
        s_p[b * H_ + h] = sp;
    }
}

// ---------------------------------------------------------------------------
// Kernel 2: out[b,h,w] = sum_e Wcat[e]*edges[b,e,h,w] + s_t[b,h] + s_p[b,w]
//
// DRAM-locality restructure: each block owns a CONTIGUOUS 2048-float4 (32 KB)
// chunk of one b's (h,w) plane = 8 full h-rows. For each e-plane it issues 8
// back-to-back wave-loads covering 32 KB sequential, then moves to the next
// plane. Grid = exactly 1024 blocks (4/CU). s_t is uniform per r (scalar
// loads); s_p loaded once per thread, reused for all 8 rows. Nontemporal
// loads/stores keep the 537 MB stream out of L2/L3.
// ---------------------------------------------------------------------------
#define R_    8              // h-rows (256-float4 chunks) per block
#define HH4_  (H_ * H_ / 4)  // 262144 float4 per (b,e) plane

__global__ __launch_bounds__(256) void affinity_main_kernel(
    const float* __restrict__ edges,  // (B, E, H, H)
    const float* __restrict__ Wcat,   // first E entries = w_e
    const float* __restrict__ s_t,    // (B, H)
    const float* __restrict__ s_p,    // (B, H)
    float* __restrict__ out)          // (B, H, H) flat
{
    const int tid  = threadIdx.x;
    const int bid  = blockIdx.x;          // 0 .. 1023
    const int b    = bid >> 7;            // 128 chunks per b
    const int rem0 = (bid & 127) << 11;   // chunk start, in float4 units (*2048)
    const int h0   = rem0 >> 8;           // first h-row of this chunk (8 rows)

    float we[E_];
    #pragma unroll
    for (int e = 0; e < E_; ++e) we[e] = Wcat[e];

    // Initialize accumulators with s_t[h] + s_p[w] (saves the epilogue adds).
    const f4_t sp = ((const f4_t*)s_p)[b * (H_ / 4) + tid];
    f4_t acc[R_];
    #pragma unroll
    for (int r = 0; r < R_; ++r) {
        const float st = s_t[b * H_ + h0 + r];   // uniform across wave -> s_load
        acc[r] = sp + st;
    }

    const f4_t* ebase = (const f4_t*)edges
                      + (size_t)b * E_ * HH4_ + rem0 + tid;

    #pragma unroll
    for (int e = 0; e < E_; ++e) {
        const f4_t* pe = ebase + (size_t)e * HH4_;
        f4_t ev[R_];
        #pragma unroll
        for (int r = 0; r < R_; ++r)
            ev[r] = __builtin_nontemporal_load(&pe[r * 256]);
        #pragma unroll
        for (int r = 0; r < R_; ++r)
            acc[r] += we[e] * ev[r];
    }

    f4_t* o = (f4_t*)out + (size_t)b * HH4_ + rem0 + tid;
    #pragma unroll
    for (int r = 0; r < R_; ++r)
        __builtin_nontemporal_store(acc[r], &o[r * 256]);
}

extern "C" void kernel_launch(void* const* d_in, const int* in_sizes, int n_in,
                              void* d_out, int out_size, void* d_ws, size_t ws_size,
                              hipStream_t stream) {
    // Inputs in setup_inputs() order:
    //   0: adj  (B,H,H)    f32 -- UNUSED by the reference
    //   1: edges(B,E,H,H)  f32
    //   2: x    (B,NIN,H)  f32
    //   3: Wt   (C,NIN)    f32
    //   4: Wp   (C,NIN)    f32
    //   5: Wcat (E+2C,)    f32
    const float* edges = (const float*)d_in[1];
    const float* x     = (const float*)d_in[2];
    const float* Wt    = (const float*)d_in[3];
    const float* Wp    = (const float*)d_in[4];
    const float* Wcat  = (const float*)d_in[5];
    float* out = (float*)d_out;

    float* s_t = (float*)d_ws;            // B*H floats = 32 KB
    float* s_p = s_t + B_ * H_;           // B*H floats = 32 KB

    compute_s_kernel<<<B_ * (H_ / 64), 256, 0, stream>>>(x, Wt, Wp, Wcat, s_t, s_p);

    const int nblk = B_ * (HH4_ / (256 * R_));   // 8 * 128 = 1024
    affinity_main_kernel<<<nblk, 256, 0, stream>>>(edges, Wcat, s_t, s_p, out);
}